// Round 1
// baseline (765.385 us; speedup 1.0000x reference)
//
#include <hip/hip_runtime.h>

#define F_IN 128
#define HID  64
#define NCLS 16

// ---------- degree: atomic count of in-edges ----------
__global__ void deg_kernel(const int* __restrict__ dst, float* __restrict__ deg, int E) {
    int i = blockIdx.x * blockDim.x + threadIdx.x;
    if (i < E) atomicAdd(&deg[dst[i]], 1.0f);
}

// ---------- dis = rsqrt(deg), in place ----------
__global__ void dis_kernel(float* deg, int N) {
    int i = blockIdx.x * blockDim.x + threadIdx.x;
    if (i < N) {
        float d = deg[i];
        deg[i] = d > 0.0f ? rsqrtf(fmaxf(d, 1.0f)) : 0.0f;
    }
}

// ---------- h1s[n][j] = (x[n] . W1[:,j]) * dis[n] ----------
// block = 256 threads = 4 rows x 64 cols. W1 (32KB) + 4 x-rows (2KB) in LDS.
__global__ __launch_bounds__(256) void gemm1_kernel(
        const float* __restrict__ x, const float* __restrict__ W1,
        const float* __restrict__ dis, float* __restrict__ h1s, int N) {
    __shared__ float Ws[F_IN * HID];
    __shared__ float xs[4][F_IN];
    int tid = threadIdx.x;

    // load W1 -> LDS (2048 float4 by 256 threads)
    for (int i = tid; i < F_IN * HID / 4; i += 256)
        ((float4*)Ws)[i] = ((const float4*)W1)[i];

    int row0 = blockIdx.x * 4;
    // load 4 x rows -> LDS (128 float4 total)
    if (tid < 128) {
        int r = tid >> 5;          // 32 float4 per row
        int c = tid & 31;
        int row = row0 + r;
        float4 v = make_float4(0.f, 0.f, 0.f, 0.f);
        if (row < N) v = ((const float4*)x)[(size_t)row * (F_IN / 4) + c];
        ((float4*)xs[r])[c] = v;
    }
    __syncthreads();

    int r = tid >> 6;   // 0..3
    int j = tid & 63;
    int row = row0 + r;
    float acc = 0.f;
    #pragma unroll
    for (int k = 0; k < F_IN; k++)
        acc += xs[r][k] * Ws[k * HID + j];
    if (row < N) h1s[(size_t)row * HID + j] = acc * dis[row];
}

// ---------- layer-1 aggregation: one wave per edge, lane = dim ----------
__global__ __launch_bounds__(256) void agg1_kernel(
        const int* __restrict__ src, const int* __restrict__ dst,
        const float* __restrict__ h1s, float* __restrict__ acc1, int E) {
    int t = blockIdx.x * blockDim.x + threadIdx.x;
    int e = t >> 6;
    int lane = t & 63;
    if (e < E) {
        int s = src[e];
        int d = dst[e];
        float v = h1s[(size_t)s * HID + lane];
        atomicAdd(&acc1[(size_t)d * HID + lane], v);
    }
}

// ---------- fused: relu(dis*acc1+b1) -> @W2 -> *dis ----------
// block = 256 = 4 waves, one node per wave.
__global__ __launch_bounds__(256) void fused2_kernel(
        const float* __restrict__ acc1, const float* __restrict__ dis,
        const float* __restrict__ b1, const float* __restrict__ W2,
        float* __restrict__ h2s, int N) {
    __shared__ float W2s[HID * NCLS];   // 4KB
    __shared__ float ts[4][HID];
    int tid = threadIdx.x;
    for (int i = tid; i < HID * NCLS; i += 256) W2s[i] = W2[i];

    int w = tid >> 6;
    int lane = tid & 63;
    int n = blockIdx.x * 4 + w;
    float dn = (n < N) ? dis[n] : 0.f;
    float t = 0.f;
    if (n < N) t = fmaxf(dn * acc1[(size_t)n * HID + lane] + b1[lane], 0.f);
    ts[w][lane] = t;
    __syncthreads();

    // lane = q*16 + c : partial dot over quarter q, cols c
    int q = lane >> 4;
    int c = lane & 15;
    float p = 0.f;
    #pragma unroll
    for (int jj = 0; jj < 16; jj++) {
        int j = q * 16 + jj;
        p += ts[w][j] * W2s[j * NCLS + c];
    }
    p += __shfl_xor(p, 16, 64);
    p += __shfl_xor(p, 32, 64);
    if (n < N && q == 0) h2s[(size_t)n * NCLS + c] = p * dn;
}

// ---------- layer-2 aggregation: 16 lanes per edge ----------
__global__ __launch_bounds__(256) void agg2_kernel(
        const int* __restrict__ src, const int* __restrict__ dst,
        const float* __restrict__ h2s, float* __restrict__ out, int E) {
    int t = blockIdx.x * blockDim.x + threadIdx.x;
    int e = t >> 4;
    int c = t & 15;
    if (e < E) {
        int s = src[e];
        int d = dst[e];
        atomicAdd(&out[(size_t)d * NCLS + c], h2s[(size_t)s * NCLS + c]);
    }
}

// ---------- final: out = dis*out + b2, in place ----------
__global__ void final_kernel(float* out, const float* __restrict__ dis,
                             const float* __restrict__ b2, int N) {
    int t = blockIdx.x * blockDim.x + threadIdx.x;
    if (t < N * NCLS) {
        int n = t >> 4;
        int c = t & 15;
        out[t] = dis[n] * out[t] + b2[c];
    }
}

extern "C" void kernel_launch(void* const* d_in, const int* in_sizes, int n_in,
                              void* d_out, int out_size, void* d_ws, size_t ws_size,
                              hipStream_t stream) {
    const float* x   = (const float*)d_in[0];
    const int*   src = (const int*)  d_in[1];
    const int*   dst = (const int*)  d_in[2];
    const float* W1  = (const float*)d_in[3];
    const float* b1  = (const float*)d_in[4];
    const float* W2  = (const float*)d_in[5];
    const float* b2  = (const float*)d_in[6];
    float* out = (float*)d_out;
    int E = in_sizes[1];
    int N = in_sizes[0] / F_IN;

    char* ws = (char*)d_ws;
    size_t o0 = 0;                                             // dis: N floats
    size_t o1 = (o0 + (size_t)N * 4 + 255) & ~(size_t)255;     // h1s: N*HID
    size_t o2 = (o1 + (size_t)N * HID * 4 + 255) & ~(size_t)255; // acc1: N*HID
    size_t o3 = (o2 + (size_t)N * HID * 4 + 255) & ~(size_t)255; // h2s: N*NCLS
    float* dis  = (float*)(ws + o0);
    float* h1s  = (float*)(ws + o1);
    float* acc1 = (float*)(ws + o2);
    float* h2s  = (float*)(ws + o3);

    hipMemsetAsync(dis,  0, (size_t)N * 4, stream);
    hipMemsetAsync(acc1, 0, (size_t)N * HID * 4, stream);
    hipMemsetAsync(out,  0, (size_t)N * NCLS * 4, stream);

    deg_kernel<<<(E + 255) / 256, 256, 0, stream>>>(dst, dis, E);
    dis_kernel<<<(N + 255) / 256, 256, 0, stream>>>(dis, N);
    gemm1_kernel<<<(N + 3) / 4, 256, 0, stream>>>(x, W1, dis, h1s, N);
    agg1_kernel<<<(E * 64 + 255) / 256, 256, 0, stream>>>(src, dst, h1s, acc1, E);
    fused2_kernel<<<(N + 3) / 4, 256, 0, stream>>>(acc1, dis, b1, W2, h2s, N);
    agg2_kernel<<<(E * 16 + 255) / 256, 256, 0, stream>>>(src, dst, h2s, out, E);
    final_kernel<<<(N * NCLS + 255) / 256, 256, 0, stream>>>(out, dis, b2, N);
}

// Round 2
// 738.083 us; speedup vs baseline: 1.0370x; 1.0370x over previous
//
#include <hip/hip_runtime.h>

#define F_IN 128
#define HID  64
#define NCLS 16

// ---------- degree: atomic int count of in-edges ----------
__global__ void deg_kernel(const int* __restrict__ dst, int* __restrict__ deg, int E) {
    int i = blockIdx.x * blockDim.x + threadIdx.x;
    if (i < E) atomicAdd(&deg[dst[i]], 1);
}

// ---------- single-block exclusive scan of deg -> row_ptr (and cursor copy) ----------
__global__ __launch_bounds__(1024) void scan_kernel(const int* __restrict__ deg,
                                                    int* __restrict__ row_ptr,
                                                    int* __restrict__ cursor,
                                                    int N, int E) {
    __shared__ int sums[1024];
    int tid = threadIdx.x;
    int C = (N + 1023) / 1024;
    int beg = tid * C;
    int end = min(beg + C, N);
    int s = 0;
    for (int i = beg; i < end; i++) s += deg[i];
    sums[tid] = s;
    __syncthreads();
    // Hillis-Steele inclusive scan over 1024 partials
    for (int off = 1; off < 1024; off <<= 1) {
        int v = (tid >= off) ? sums[tid - off] : 0;
        __syncthreads();
        sums[tid] += v;
        __syncthreads();
    }
    int run = (tid == 0) ? 0 : sums[tid - 1];   // exclusive prefix of this chunk
    for (int i = beg; i < end; i++) {
        row_ptr[i] = run;
        cursor[i]  = run;
        run += deg[i];
    }
    if (end == N) row_ptr[N] = E;
}

// ---------- dis = rsqrt(deg) ----------
__global__ void dis_kernel(const int* __restrict__ deg, float* __restrict__ dis, int N) {
    int i = blockIdx.x * blockDim.x + threadIdx.x;
    if (i < N) {
        float d = (float)deg[i];
        dis[i] = d > 0.0f ? rsqrtf(fmaxf(d, 1.0f)) : 0.0f;
    }
}

// ---------- CSR fill: csr_src grouped by dst ----------
__global__ void fill_kernel(const int* __restrict__ src, const int* __restrict__ dst,
                            int* __restrict__ cursor, int* __restrict__ csr_src, int E) {
    int e = blockIdx.x * blockDim.x + threadIdx.x;
    if (e < E) {
        int d = dst[e];
        int pos = atomicAdd(&cursor[d], 1);
        csr_src[pos] = src[e];
    }
}

// ---------- h1s[n][j] = (x[n] . W1[:,j]) * dis[n] ----------
__global__ __launch_bounds__(256) void gemm1_kernel(
        const float* __restrict__ x, const float* __restrict__ W1,
        const float* __restrict__ dis, float* __restrict__ h1s, int N) {
    __shared__ float Ws[F_IN * HID];
    __shared__ float xs[4][F_IN];
    int tid = threadIdx.x;

    for (int i = tid; i < F_IN * HID / 4; i += 256)
        ((float4*)Ws)[i] = ((const float4*)W1)[i];

    int row0 = blockIdx.x * 4;
    if (tid < 128) {
        int r = tid >> 5;
        int c = tid & 31;
        int row = row0 + r;
        float4 v = make_float4(0.f, 0.f, 0.f, 0.f);
        if (row < N) v = ((const float4*)x)[(size_t)row * (F_IN / 4) + c];
        ((float4*)xs[r])[c] = v;
    }
    __syncthreads();

    int r = tid >> 6;
    int j = tid & 63;
    int row = row0 + r;
    float acc = 0.f;
    #pragma unroll
    for (int k = 0; k < F_IN; k++)
        acc += xs[r][k] * Ws[k * HID + j];
    if (row < N) h1s[(size_t)row * HID + j] = acc * dis[row];
}

// ---------- fused layer-1 agg + ReLU + W2 GEMM: one wave per node ----------
// acc[lane] = sum over in-edges of h1s[src][lane]  (pull, no atomics)
// t = relu(dis*acc + b1);  h2s = (t @ W2) * dis
__global__ __launch_bounds__(256) void agg1_fused(
        const int* __restrict__ row_ptr, const int* __restrict__ csr_src,
        const float* __restrict__ h1s, const float* __restrict__ dis,
        const float* __restrict__ b1, const float* __restrict__ W2,
        float* __restrict__ h2s, int N) {
    __shared__ float W2s[HID * NCLS];   // 4 KB
    __shared__ float ts[4][HID];
    int tid = threadIdx.x;
    for (int i = tid; i < HID * NCLS; i += 256) W2s[i] = W2[i];
    __syncthreads();

    int w = tid >> 6;
    int lane = tid & 63;
    int n = blockIdx.x * 4 + w;

    float acc = 0.f;
    float dn = 0.f;
    if (n < N) {
        dn = dis[n];
        int beg = row_ptr[n];
        int end = row_ptr[n + 1];
        int i = beg;
        for (; i + 4 <= end; i += 4) {
            int s0 = csr_src[i];
            int s1 = csr_src[i + 1];
            int s2 = csr_src[i + 2];
            int s3 = csr_src[i + 3];
            float v0 = h1s[(size_t)s0 * HID + lane];
            float v1 = h1s[(size_t)s1 * HID + lane];
            float v2 = h1s[(size_t)s2 * HID + lane];
            float v3 = h1s[(size_t)s3 * HID + lane];
            acc += v0 + v1 + v2 + v3;
        }
        for (; i < end; i++)
            acc += h1s[(size_t)csr_src[i] * HID + lane];
    }

    float t = fmaxf(dn * acc + b1[lane], 0.f);
    ts[w][lane] = t;   // wave-local LDS (lockstep within wave; compiler inserts lgkmcnt)

    int q = lane >> 4;
    int c = lane & 15;
    float p = 0.f;
    #pragma unroll
    for (int jj = 0; jj < 16; jj++) {
        int j = q * 16 + jj;
        p += ts[w][j] * W2s[j * NCLS + c];
    }
    p += __shfl_xor(p, 16, 64);
    p += __shfl_xor(p, 32, 64);
    if (n < N && q == 0) h2s[(size_t)n * NCLS + c] = p * dn;
}

// ---------- fused layer-2 agg + epilogue: one wave per node, 4 edges/iter ----------
__global__ __launch_bounds__(256) void agg2_fused(
        const int* __restrict__ row_ptr, const int* __restrict__ csr_src,
        const float* __restrict__ h2s, const float* __restrict__ dis,
        const float* __restrict__ b2, float* __restrict__ out, int N) {
    int tid = blockIdx.x * blockDim.x + threadIdx.x;
    int n = tid >> 6;
    int lane = tid & 63;
    if (n >= N) return;
    int j = lane >> 4;   // edge slot within iteration
    int c = lane & 15;   // class index
    int beg = row_ptr[n];
    int end = row_ptr[n + 1];
    float acc = 0.f;
    for (int i = beg + j; i < end; i += 4) {
        int s = csr_src[i];
        acc += h2s[(size_t)s * NCLS + c];
    }
    acc += __shfl_xor(acc, 16, 64);
    acc += __shfl_xor(acc, 32, 64);
    if (j == 0) out[(size_t)n * NCLS + c] = dis[n] * acc + b2[c];
}

extern "C" void kernel_launch(void* const* d_in, const int* in_sizes, int n_in,
                              void* d_out, int out_size, void* d_ws, size_t ws_size,
                              hipStream_t stream) {
    const float* x   = (const float*)d_in[0];
    const int*   src = (const int*)  d_in[1];
    const int*   dst = (const int*)  d_in[2];
    const float* W1  = (const float*)d_in[3];
    const float* b1  = (const float*)d_in[4];
    const float* W2  = (const float*)d_in[5];
    const float* b2  = (const float*)d_in[6];
    float* out = (float*)d_out;
    int E = in_sizes[1];
    int N = in_sizes[0] / F_IN;

    char* ws = (char*)d_ws;
    size_t off = 0;
    auto alloc = [&](size_t bytes) { size_t o = off; off = (off + bytes + 255) & ~(size_t)255; return (void*)(ws + o); };
    int*   deg     = (int*)  alloc((size_t)N * 4);
    int*   row_ptr = (int*)  alloc((size_t)(N + 1) * 4);
    int*   cursor  = (int*)  alloc((size_t)N * 4);
    int*   csr_src = (int*)  alloc((size_t)E * 4);
    float* dis     = (float*)alloc((size_t)N * 4);
    float* h1s     = (float*)alloc((size_t)N * HID * 4);
    float* h2s     = (float*)alloc((size_t)N * NCLS * 4);

    hipMemsetAsync(deg, 0, (size_t)N * 4, stream);

    deg_kernel <<<(E + 255) / 256, 256, 0, stream>>>(dst, deg, E);
    scan_kernel<<<1, 1024, 0, stream>>>(deg, row_ptr, cursor, N, E);
    dis_kernel <<<(N + 255) / 256, 256, 0, stream>>>(deg, dis, N);
    fill_kernel<<<(E + 255) / 256, 256, 0, stream>>>(src, dst, cursor, csr_src, E);
    gemm1_kernel<<<(N + 3) / 4, 256, 0, stream>>>(x, W1, dis, h1s, N);
    agg1_fused <<<(N + 3) / 4, 256, 0, stream>>>(row_ptr, csr_src, h1s, dis, b1, W2, h2s, N);
    agg2_fused <<<(N + 3) / 4, 256, 0, stream>>>(row_ptr, csr_src, h2s, dis, b2, out, N);
}

// Round 3
// 509.585 us; speedup vs baseline: 1.5020x; 1.4484x over previous
//
#include <hip/hip_runtime.h>

#define F_IN 128
#define HID  64
#define NCLS 16

// ---------- degree: atomic int count of in-edges ----------
__global__ void deg_kernel(const int* __restrict__ dst, int* __restrict__ deg, int E) {
    int i = blockIdx.x * blockDim.x + threadIdx.x;
    if (i < E) atomicAdd(&deg[dst[i]], 1);
}

// ---------- hierarchical scan, stage 1: per-block reduce (1024 elems/block) ----------
__global__ __launch_bounds__(1024) void scan1_kernel(const int* __restrict__ deg,
                                                     int* __restrict__ blk_sums, int N) {
    __shared__ int red[1024];
    int tid = threadIdx.x;
    int i = blockIdx.x * 1024 + tid;
    red[tid] = (i < N) ? deg[i] : 0;
    __syncthreads();
    for (int off = 512; off > 0; off >>= 1) {
        if (tid < off) red[tid] += red[tid + off];
        __syncthreads();
    }
    if (tid == 0) blk_sums[blockIdx.x] = red[0];
}

// ---------- stage 2: single-block exclusive scan of block sums (nb <= 1024) ----------
__global__ __launch_bounds__(1024) void scan2_kernel(int* __restrict__ blk_sums, int nb) {
    __shared__ int s[1024];
    int tid = threadIdx.x;
    s[tid] = (tid < nb) ? blk_sums[tid] : 0;
    __syncthreads();
    for (int off = 1; off < 1024; off <<= 1) {
        int t = (tid >= off) ? s[tid - off] : 0;
        __syncthreads();
        s[tid] += t;
        __syncthreads();
    }
    if (tid < nb) blk_sums[tid] = (tid == 0) ? 0 : s[tid - 1];
}

// ---------- stage 3: block-local inclusive scan + offset -> row_ptr, cursor ----------
__global__ __launch_bounds__(1024) void scan3_kernel(const int* __restrict__ deg,
                                                     const int* __restrict__ blk_sums,
                                                     int* __restrict__ row_ptr,
                                                     int* __restrict__ cursor, int N, int E) {
    __shared__ int s[1024];
    int tid = threadIdx.x;
    int i = blockIdx.x * 1024 + tid;
    int v = (i < N) ? deg[i] : 0;
    s[tid] = v;
    __syncthreads();
    for (int off = 1; off < 1024; off <<= 1) {
        int t = (tid >= off) ? s[tid - off] : 0;
        __syncthreads();
        s[tid] += t;
        __syncthreads();
    }
    int excl = s[tid] - v + blk_sums[blockIdx.x];
    if (i < N) { row_ptr[i] = excl; cursor[i] = excl; }
    if (i == N - 1) row_ptr[N] = E;
}

// ---------- dis = rsqrt(deg) ----------
__global__ void dis_kernel(const int* __restrict__ deg, float* __restrict__ dis, int N) {
    int i = blockIdx.x * blockDim.x + threadIdx.x;
    if (i < N) {
        float d = (float)deg[i];
        dis[i] = d > 0.0f ? rsqrtf(fmaxf(d, 1.0f)) : 0.0f;
    }
}

// ---------- CSR fill: csr_src grouped by dst ----------
__global__ void fill_kernel(const int* __restrict__ src, const int* __restrict__ dst,
                            int* __restrict__ cursor, int* __restrict__ csr_src, int E) {
    int e = blockIdx.x * blockDim.x + threadIdx.x;
    if (e < E) {
        int d = dst[e];
        int pos = atomicAdd(&cursor[d], 1);
        csr_src[pos] = src[e];
    }
}

// ---------- h1s[n][j] = (x[n] . W1[:,j]) * dis[n] ----------
__global__ __launch_bounds__(256) void gemm1_kernel(
        const float* __restrict__ x, const float* __restrict__ W1,
        const float* __restrict__ dis, float* __restrict__ h1s, int N) {
    __shared__ float Ws[F_IN * HID];
    __shared__ float xs[4][F_IN];
    int tid = threadIdx.x;

    for (int i = tid; i < F_IN * HID / 4; i += 256)
        ((float4*)Ws)[i] = ((const float4*)W1)[i];

    int row0 = blockIdx.x * 4;
    if (tid < 128) {
        int r = tid >> 5;
        int c = tid & 31;
        int row = row0 + r;
        float4 v = make_float4(0.f, 0.f, 0.f, 0.f);
        if (row < N) v = ((const float4*)x)[(size_t)row * (F_IN / 4) + c];
        ((float4*)xs[r])[c] = v;
    }
    __syncthreads();

    int r = tid >> 6;
    int j = tid & 63;
    int row = row0 + r;
    float acc = 0.f;
    #pragma unroll
    for (int k = 0; k < F_IN; k++)
        acc += xs[r][k] * Ws[k * HID + j];
    if (row < N) h1s[(size_t)row * HID + j] = acc * dis[row];
}

// ---------- fused layer-1 agg + ReLU + W2 GEMM: one wave per node ----------
__global__ __launch_bounds__(256) void agg1_fused(
        const int* __restrict__ row_ptr, const int* __restrict__ csr_src,
        const float* __restrict__ h1s, const float* __restrict__ dis,
        const float* __restrict__ b1, const float* __restrict__ W2,
        float* __restrict__ h2s, int N) {
    __shared__ float W2s[HID * NCLS];   // 4 KB
    __shared__ float ts[4][HID];
    int tid = threadIdx.x;
    for (int i = tid; i < HID * NCLS; i += 256) W2s[i] = W2[i];
    __syncthreads();

    int w = tid >> 6;
    int lane = tid & 63;
    int n = blockIdx.x * 4 + w;

    float acc = 0.f;
    float dn = 0.f;
    if (n < N) {
        dn = dis[n];
        int beg = row_ptr[n];
        int end = row_ptr[n + 1];
        int i = beg;
        for (; i + 4 <= end; i += 4) {
            int s0 = csr_src[i];
            int s1 = csr_src[i + 1];
            int s2 = csr_src[i + 2];
            int s3 = csr_src[i + 3];
            float v0 = h1s[(size_t)s0 * HID + lane];
            float v1 = h1s[(size_t)s1 * HID + lane];
            float v2 = h1s[(size_t)s2 * HID + lane];
            float v3 = h1s[(size_t)s3 * HID + lane];
            acc += v0 + v1 + v2 + v3;
        }
        for (; i < end; i++)
            acc += h1s[(size_t)csr_src[i] * HID + lane];
    }

    float t = fmaxf(dn * acc + b1[lane], 0.f);
    ts[w][lane] = t;

    int q = lane >> 4;
    int c = lane & 15;
    float p = 0.f;
    #pragma unroll
    for (int jj = 0; jj < 16; jj++) {
        int j = q * 16 + jj;
        p += ts[w][j] * W2s[j * NCLS + c];
    }
    p += __shfl_xor(p, 16, 64);
    p += __shfl_xor(p, 32, 64);
    if (n < N && q == 0) h2s[(size_t)n * NCLS + c] = p * dn;
}

// ---------- fused layer-2 agg + epilogue: one wave per node, 4 edges/iter ----------
__global__ __launch_bounds__(256) void agg2_fused(
        const int* __restrict__ row_ptr, const int* __restrict__ csr_src,
        const float* __restrict__ h2s, const float* __restrict__ dis,
        const float* __restrict__ b2, float* __restrict__ out, int N) {
    int tid = blockIdx.x * blockDim.x + threadIdx.x;
    int n = tid >> 6;
    int lane = tid & 63;
    if (n >= N) return;
    int j = lane >> 4;
    int c = lane & 15;
    int beg = row_ptr[n];
    int end = row_ptr[n + 1];
    float acc = 0.f;
    for (int i = beg + j; i < end; i += 4) {
        int s = csr_src[i];
        acc += h2s[(size_t)s * NCLS + c];
    }
    acc += __shfl_xor(acc, 16, 64);
    acc += __shfl_xor(acc, 32, 64);
    if (j == 0) out[(size_t)n * NCLS + c] = dis[n] * acc + b2[c];
}

extern "C" void kernel_launch(void* const* d_in, const int* in_sizes, int n_in,
                              void* d_out, int out_size, void* d_ws, size_t ws_size,
                              hipStream_t stream) {
    const float* x   = (const float*)d_in[0];
    const int*   src = (const int*)  d_in[1];
    const int*   dst = (const int*)  d_in[2];
    const float* W1  = (const float*)d_in[3];
    const float* b1  = (const float*)d_in[4];
    const float* W2  = (const float*)d_in[5];
    const float* b2  = (const float*)d_in[6];
    float* out = (float*)d_out;
    int E = in_sizes[1];
    int N = in_sizes[0] / F_IN;
    int nb = (N + 1023) / 1024;   // scan blocks (98 for N=100k, fits in 1024)

    char* ws = (char*)d_ws;
    size_t off = 0;
    auto alloc = [&](size_t bytes) { size_t o = off; off = (off + bytes + 255) & ~(size_t)255; return (void*)(ws + o); };
    int*   deg      = (int*)  alloc((size_t)N * 4);
    int*   row_ptr  = (int*)  alloc((size_t)(N + 1) * 4);
    int*   cursor   = (int*)  alloc((size_t)N * 4);
    int*   csr_src  = (int*)  alloc((size_t)E * 4);
    int*   blk_sums = (int*)  alloc((size_t)nb * 4);
    float* dis      = (float*)alloc((size_t)N * 4);
    float* h1s      = (float*)alloc((size_t)N * HID * 4);
    float* h2s      = (float*)alloc((size_t)N * NCLS * 4);

    hipMemsetAsync(deg, 0, (size_t)N * 4, stream);

    deg_kernel  <<<(E + 255) / 256, 256, 0, stream>>>(dst, deg, E);
    scan1_kernel<<<nb, 1024, 0, stream>>>(deg, blk_sums, N);
    scan2_kernel<<<1, 1024, 0, stream>>>(blk_sums, nb);
    scan3_kernel<<<nb, 1024, 0, stream>>>(deg, blk_sums, row_ptr, cursor, N, E);
    dis_kernel  <<<(N + 255) / 256, 256, 0, stream>>>(deg, dis, N);
    fill_kernel <<<(E + 255) / 256, 256, 0, stream>>>(src, dst, cursor, csr_src, E);
    gemm1_kernel<<<(N + 3) / 4, 256, 0, stream>>>(x, W1, dis, h1s, N);
    agg1_fused  <<<(N + 3) / 4, 256, 0, stream>>>(row_ptr, csr_src, h1s, dis, b1, W2, h2s, N);
    agg2_fused  <<<(N + 3) / 4, 256, 0, stream>>>(row_ptr, csr_src, h2s, dis, b2, out, N);
}

// Round 4
// 381.044 us; speedup vs baseline: 2.0086x; 1.3373x over previous
//
#include <hip/hip_runtime.h>

#define F_IN 128
#define HID  64
#define NCLS 16

#define BSHIFT 8            // 256 nodes per bucket
#define BNODES 256
#define NB_MAX 512          // max buckets (N<=128k)
#define CHUNK  8192         // edges per scatter block
#define CAP    8192         // max edges per bucket in LDS (mean 4352, 50+ sigma margin)

// ---------- pass 1: global bucket histogram ----------
__global__ __launch_bounds__(256) void hist_kernel(const int* __restrict__ dst,
                                                   int* __restrict__ bucket_count,
                                                   int E, int NB) {
    __shared__ int hist[NB_MAX];
    int tid = threadIdx.x;
    for (int i = tid; i < NB; i += 256) hist[i] = 0;
    __syncthreads();
    int cb = blockIdx.x * CHUNK;
    for (int k = 0; k < CHUNK / 256; k++) {
        int e = cb + k * 256 + tid;
        if (e < E) atomicAdd(&hist[dst[e] >> BSHIFT], 1);
    }
    __syncthreads();
    for (int i = tid; i < NB; i += 256)
        if (hist[i]) atomicAdd(&bucket_count[i], hist[i]);
}

// ---------- pass 2: single-block scan of bucket counts ----------
__global__ __launch_bounds__(512) void scan_buckets(const int* __restrict__ bucket_count,
                                                    int* __restrict__ bucket_base,
                                                    int* __restrict__ bucket_cursor,
                                                    int* __restrict__ row_ptr,
                                                    int NB, int N, int E) {
    __shared__ int s[512];
    int tid = threadIdx.x;
    int v = (tid < NB) ? bucket_count[tid] : 0;
    s[tid] = v;
    __syncthreads();
    for (int off = 1; off < 512; off <<= 1) {
        int t = (tid >= off) ? s[tid - off] : 0;
        __syncthreads();
        s[tid] += t;
        __syncthreads();
    }
    if (tid < NB) {
        int excl = s[tid] - v;
        bucket_base[tid]   = excl;
        bucket_cursor[tid] = excl;
    }
    if (tid == 0) { bucket_base[NB] = E; row_ptr[N] = E; }
}

// ---------- pass 3: partition edges into bucket regions (run-coalesced) ----------
__global__ __launch_bounds__(256) void scatter_kernel(const int* __restrict__ src,
                                                      const int* __restrict__ dst,
                                                      int* __restrict__ bucket_cursor,
                                                      unsigned int* __restrict__ part,
                                                      int E, int NB) {
    __shared__ int hist[NB_MAX];
    __shared__ int base_s[NB_MAX];
    int tid = threadIdx.x;
    for (int i = tid; i < NB; i += 256) hist[i] = 0;
    __syncthreads();
    int cb = blockIdx.x * CHUNK;
    for (int k = 0; k < CHUNK / 256; k++) {
        int e = cb + k * 256 + tid;
        if (e < E) atomicAdd(&hist[dst[e] >> BSHIFT], 1);
    }
    __syncthreads();
    // reserve contiguous space per bucket for this block, reset local counters
    for (int i = tid; i < NB; i += 256) {
        int c = hist[i];
        base_s[i] = c ? atomicAdd(&bucket_cursor[i], c) : 0;
        hist[i] = 0;
    }
    __syncthreads();
    for (int k = 0; k < CHUNK / 256; k++) {
        int e = cb + k * 256 + tid;
        if (e < E) {
            int d = dst[e];
            int b = d >> BSHIFT;
            int pos = base_s[b] + atomicAdd(&hist[b], 1);
            part[pos] = ((unsigned int)(d & (BNODES - 1)) << 24) | (unsigned int)src[e];
        }
    }
}

// ---------- pass 4: per-bucket counting sort -> csr_src, row_ptr, dis ----------
__global__ __launch_bounds__(256) void csr_build(const unsigned int* __restrict__ part,
                                                 const int* __restrict__ bucket_base,
                                                 int* __restrict__ csr_src,
                                                 int* __restrict__ row_ptr,
                                                 float* __restrict__ dis,
                                                 int N) {
    __shared__ unsigned int eL[CAP];
    __shared__ unsigned int outL[CAP];
    __shared__ int cnt[BNODES];
    __shared__ int sc[BNODES];
    __shared__ int cur[BNODES];
    int tid = threadIdx.x;
    int b = blockIdx.x;
    int eB = bucket_base[b];
    int eN = bucket_base[b + 1] - eB;
    if (eN > CAP) eN = CAP;   // statistically impossible; guards LDS OOB

    cnt[tid] = 0;
    __syncthreads();
    for (int i = tid; i < eN; i += 256) {
        unsigned int v = part[eB + i];
        eL[i] = v;
        atomicAdd(&cnt[v >> 24], 1);
    }
    __syncthreads();
    // inclusive scan of cnt[256]
    int myc = cnt[tid];
    sc[tid] = myc;
    __syncthreads();
    for (int off = 1; off < 256; off <<= 1) {
        int t = (tid >= off) ? sc[tid - off] : 0;
        __syncthreads();
        sc[tid] += t;
        __syncthreads();
    }
    int excl = sc[tid] - myc;
    cur[tid] = excl;
    int gnode = b * BNODES + tid;
    if (gnode < N) {
        row_ptr[gnode] = eB + excl;
        float d = (float)myc;
        dis[gnode] = d > 0.0f ? rsqrtf(fmaxf(d, 1.0f)) : 0.0f;
    }
    __syncthreads();
    // scatter within LDS
    for (int i = tid; i < eN; i += 256) {
        unsigned int v = eL[i];
        int pos = atomicAdd(&cur[v >> 24], 1);
        outL[pos] = v & 0xFFFFFFu;   // src (< 2^17)
    }
    __syncthreads();
    // coalesced write-out
    for (int i = tid; i < eN; i += 256)
        csr_src[eB + i] = (int)outL[i];
}

// ---------- h1s[n][j] = (x[n] . W1[:,j]) * dis[n] ----------
__global__ __launch_bounds__(256) void gemm1_kernel(
        const float* __restrict__ x, const float* __restrict__ W1,
        const float* __restrict__ dis, float* __restrict__ h1s, int N) {
    __shared__ float Ws[F_IN * HID];
    __shared__ float xs[4][F_IN];
    int tid = threadIdx.x;

    for (int i = tid; i < F_IN * HID / 4; i += 256)
        ((float4*)Ws)[i] = ((const float4*)W1)[i];

    int row0 = blockIdx.x * 4;
    if (tid < 128) {
        int r = tid >> 5;
        int c = tid & 31;
        int row = row0 + r;
        float4 v = make_float4(0.f, 0.f, 0.f, 0.f);
        if (row < N) v = ((const float4*)x)[(size_t)row * (F_IN / 4) + c];
        ((float4*)xs[r])[c] = v;
    }
    __syncthreads();

    int r = tid >> 6;
    int j = tid & 63;
    int row = row0 + r;
    float acc = 0.f;
    #pragma unroll
    for (int k = 0; k < F_IN; k++)
        acc += xs[r][k] * Ws[k * HID + j];
    if (row < N) h1s[(size_t)row * HID + j] = acc * dis[row];
}

// ---------- fused layer-1 agg + ReLU + W2 GEMM: one wave per node ----------
__global__ __launch_bounds__(256) void agg1_fused(
        const int* __restrict__ row_ptr, const int* __restrict__ csr_src,
        const float* __restrict__ h1s, const float* __restrict__ dis,
        const float* __restrict__ b1, const float* __restrict__ W2,
        float* __restrict__ h2s, int N) {
    __shared__ float W2s[HID * NCLS];
    __shared__ float ts[4][HID];
    int tid = threadIdx.x;
    for (int i = tid; i < HID * NCLS; i += 256) W2s[i] = W2[i];
    __syncthreads();

    int w = tid >> 6;
    int lane = tid & 63;
    int n = blockIdx.x * 4 + w;

    float acc = 0.f;
    float dn = 0.f;
    if (n < N) {
        dn = dis[n];
        int beg = row_ptr[n];
        int end = row_ptr[n + 1];
        int i = beg;
        for (; i + 4 <= end; i += 4) {
            int s0 = csr_src[i];
            int s1 = csr_src[i + 1];
            int s2 = csr_src[i + 2];
            int s3 = csr_src[i + 3];
            float v0 = h1s[(size_t)s0 * HID + lane];
            float v1 = h1s[(size_t)s1 * HID + lane];
            float v2 = h1s[(size_t)s2 * HID + lane];
            float v3 = h1s[(size_t)s3 * HID + lane];
            acc += v0 + v1 + v2 + v3;
        }
        for (; i < end; i++)
            acc += h1s[(size_t)csr_src[i] * HID + lane];
    }

    float t = fmaxf(dn * acc + b1[lane], 0.f);
    ts[w][lane] = t;

    int q = lane >> 4;
    int c = lane & 15;
    float p = 0.f;
    #pragma unroll
    for (int jj = 0; jj < 16; jj++) {
        int j = q * 16 + jj;
        p += ts[w][j] * W2s[j * NCLS + c];
    }
    p += __shfl_xor(p, 16, 64);
    p += __shfl_xor(p, 32, 64);
    if (n < N && q == 0) h2s[(size_t)n * NCLS + c] = p * dn;
}

// ---------- fused layer-2 agg + epilogue ----------
__global__ __launch_bounds__(256) void agg2_fused(
        const int* __restrict__ row_ptr, const int* __restrict__ csr_src,
        const float* __restrict__ h2s, const float* __restrict__ dis,
        const float* __restrict__ b2, float* __restrict__ out, int N) {
    int tid = blockIdx.x * blockDim.x + threadIdx.x;
    int n = tid >> 6;
    int lane = tid & 63;
    if (n >= N) return;
    int j = lane >> 4;
    int c = lane & 15;
    int beg = row_ptr[n];
    int end = row_ptr[n + 1];
    float acc = 0.f;
    for (int i = beg + j; i < end; i += 4) {
        int s = csr_src[i];
        acc += h2s[(size_t)s * NCLS + c];
    }
    acc += __shfl_xor(acc, 16, 64);
    acc += __shfl_xor(acc, 32, 64);
    if (j == 0) out[(size_t)n * NCLS + c] = dis[n] * acc + b2[c];
}

extern "C" void kernel_launch(void* const* d_in, const int* in_sizes, int n_in,
                              void* d_out, int out_size, void* d_ws, size_t ws_size,
                              hipStream_t stream) {
    const float* x   = (const float*)d_in[0];
    const int*   src = (const int*)  d_in[1];
    const int*   dst = (const int*)  d_in[2];
    const float* W1  = (const float*)d_in[3];
    const float* b1  = (const float*)d_in[4];
    const float* W2  = (const float*)d_in[5];
    const float* b2  = (const float*)d_in[6];
    float* out = (float*)d_out;
    int E = in_sizes[1];
    int N = in_sizes[0] / F_IN;
    int NB = (N + BNODES - 1) >> BSHIFT;        // 391 for N=100k
    int nchunks = (E + CHUNK - 1) / CHUNK;      // 208 for E=1.7M

    char* ws = (char*)d_ws;
    size_t off = 0;
    auto alloc = [&](size_t bytes) { size_t o = off; off = (off + bytes + 255) & ~(size_t)255; return (void*)(ws + o); };
    int*   bucket_count  = (int*)  alloc((size_t)NB * 4);
    int*   bucket_base   = (int*)  alloc((size_t)(NB + 1) * 4);
    int*   bucket_cursor = (int*)  alloc((size_t)NB * 4);
    int*   row_ptr       = (int*)  alloc((size_t)(N + 1) * 4);
    int*   csr_src       = (int*)  alloc((size_t)E * 4);
    float* dis           = (float*)alloc((size_t)N * 4);
    float* h1s           = (float*)alloc((size_t)N * HID * 4);
    float* h2s           = (float*)alloc((size_t)N * NCLS * 4);
    // part[] aliases h1s: dead before gemm1 writes h1s (needs E*4 <= N*HID*4)
    unsigned int* part   = (unsigned int*)h1s;

    hipMemsetAsync(bucket_count, 0, (size_t)NB * 4, stream);

    hist_kernel   <<<nchunks, 256, 0, stream>>>(dst, bucket_count, E, NB);
    scan_buckets  <<<1, 512, 0, stream>>>(bucket_count, bucket_base, bucket_cursor, row_ptr, NB, N, E);
    scatter_kernel<<<nchunks, 256, 0, stream>>>(src, dst, bucket_cursor, part, E, NB);
    csr_build     <<<NB, 256, 0, stream>>>(part, bucket_base, csr_src, row_ptr, dis, N);
    gemm1_kernel  <<<(N + 3) / 4, 256, 0, stream>>>(x, W1, dis, h1s, N);
    agg1_fused    <<<(N + 3) / 4, 256, 0, stream>>>(row_ptr, csr_src, h1s, dis, b1, W2, h2s, N);
    agg2_fused    <<<(N + 3) / 4, 256, 0, stream>>>(row_ptr, csr_src, h2s, dis, b2, out, N);
}

// Round 5
// 343.048 us; speedup vs baseline: 2.2311x; 1.1108x over previous
//
#include <hip/hip_runtime.h>

#define F_IN 128
#define HID  64
#define NCLS 16

#define BSHIFT 8            // 256 nodes per bucket
#define BNODES 256
#define NB_MAX 512          // max buckets (N<=128k)
#define CHUNK  8192         // edges per scatter block
#define CAP    8192         // max edges per bucket in LDS (mean 4352, 50+ sigma margin)

// ---------- pass 1: global bucket histogram ----------
__global__ __launch_bounds__(256) void hist_kernel(const int* __restrict__ dst,
                                                   int* __restrict__ bucket_count,
                                                   int E, int NB) {
    __shared__ int hist[NB_MAX];
    int tid = threadIdx.x;
    for (int i = tid; i < NB; i += 256) hist[i] = 0;
    __syncthreads();
    int cb = blockIdx.x * CHUNK;
    for (int k = 0; k < CHUNK / 256; k++) {
        int e = cb + k * 256 + tid;
        if (e < E) atomicAdd(&hist[dst[e] >> BSHIFT], 1);
    }
    __syncthreads();
    for (int i = tid; i < NB; i += 256)
        if (hist[i]) atomicAdd(&bucket_count[i], hist[i]);
}

// ---------- pass 2: single-block scan of bucket counts ----------
__global__ __launch_bounds__(512) void scan_buckets(const int* __restrict__ bucket_count,
                                                    int* __restrict__ bucket_base,
                                                    int* __restrict__ bucket_cursor,
                                                    int* __restrict__ row_ptr,
                                                    int NB, int N, int E) {
    __shared__ int s[512];
    int tid = threadIdx.x;
    int v = (tid < NB) ? bucket_count[tid] : 0;
    s[tid] = v;
    __syncthreads();
    for (int off = 1; off < 512; off <<= 1) {
        int t = (tid >= off) ? s[tid - off] : 0;
        __syncthreads();
        s[tid] += t;
        __syncthreads();
    }
    if (tid < NB) {
        int excl = s[tid] - v;
        bucket_base[tid]   = excl;
        bucket_cursor[tid] = excl;
    }
    if (tid == 0) { bucket_base[NB] = E; row_ptr[N] = E; }
}

// ---------- pass 3: partition edges into bucket regions (run-coalesced) ----------
__global__ __launch_bounds__(256) void scatter_kernel(const int* __restrict__ src,
                                                      const int* __restrict__ dst,
                                                      int* __restrict__ bucket_cursor,
                                                      unsigned int* __restrict__ part,
                                                      int E, int NB) {
    __shared__ int hist[NB_MAX];
    __shared__ int base_s[NB_MAX];
    int tid = threadIdx.x;
    for (int i = tid; i < NB; i += 256) hist[i] = 0;
    __syncthreads();
    int cb = blockIdx.x * CHUNK;
    for (int k = 0; k < CHUNK / 256; k++) {
        int e = cb + k * 256 + tid;
        if (e < E) atomicAdd(&hist[dst[e] >> BSHIFT], 1);
    }
    __syncthreads();
    for (int i = tid; i < NB; i += 256) {
        int c = hist[i];
        base_s[i] = c ? atomicAdd(&bucket_cursor[i], c) : 0;
        hist[i] = 0;
    }
    __syncthreads();
    for (int k = 0; k < CHUNK / 256; k++) {
        int e = cb + k * 256 + tid;
        if (e < E) {
            int d = dst[e];
            int b = d >> BSHIFT;
            int pos = base_s[b] + atomicAdd(&hist[b], 1);
            part[pos] = ((unsigned int)(d & (BNODES - 1)) << 24) | (unsigned int)src[e];
        }
    }
}

// ---------- pass 4: per-bucket counting sort -> csr_src, row_ptr, dis ----------
__global__ __launch_bounds__(256) void csr_build(const unsigned int* __restrict__ part,
                                                 const int* __restrict__ bucket_base,
                                                 int* __restrict__ csr_src,
                                                 int* __restrict__ row_ptr,
                                                 float* __restrict__ dis,
                                                 int N) {
    __shared__ unsigned int eL[CAP];
    __shared__ unsigned int outL[CAP];
    __shared__ int cnt[BNODES];
    __shared__ int sc[BNODES];
    __shared__ int cur[BNODES];
    int tid = threadIdx.x;
    int b = blockIdx.x;
    int eB = bucket_base[b];
    int eN = bucket_base[b + 1] - eB;
    if (eN > CAP) eN = CAP;

    cnt[tid] = 0;
    __syncthreads();
    for (int i = tid; i < eN; i += 256) {
        unsigned int v = part[eB + i];
        eL[i] = v;
        atomicAdd(&cnt[v >> 24], 1);
    }
    __syncthreads();
    int myc = cnt[tid];
    sc[tid] = myc;
    __syncthreads();
    for (int off = 1; off < 256; off <<= 1) {
        int t = (tid >= off) ? sc[tid - off] : 0;
        __syncthreads();
        sc[tid] += t;
        __syncthreads();
    }
    int excl = sc[tid] - myc;
    cur[tid] = excl;
    int gnode = b * BNODES + tid;
    if (gnode < N) {
        row_ptr[gnode] = eB + excl;
        float d = (float)myc;
        dis[gnode] = d > 0.0f ? rsqrtf(fmaxf(d, 1.0f)) : 0.0f;
    }
    __syncthreads();
    for (int i = tid; i < eN; i += 256) {
        unsigned int v = eL[i];
        int pos = atomicAdd(&cur[v >> 24], 1);
        outL[pos] = v & 0xFFFFFFu;
    }
    __syncthreads();
    for (int i = tid; i < eN; i += 256)
        csr_src[eB + i] = (int)outL[i];
}

// ---------- gemm1: lane=row, W1 rows scalarized (wave-uniform -> s_load), ----------
// ---------- 64 acc VGPRs/lane, x staged in LDS (2 k-phases of 64)          ----------
__global__ __launch_bounds__(64) void gemm1_kernel(
        const float* __restrict__ x, const float* __restrict__ W1,
        const float* __restrict__ dis, float* __restrict__ h1s, int N) {
    __shared__ float xs[64 * 68];   // 64 rows x 64-k phase, row stride 68 floats (17 f4)
    int lane = threadIdx.x;
    int row0 = blockIdx.x * 64;
    int row = row0 + lane;

    float acc[HID];
    #pragma unroll
    for (int j = 0; j < HID; j++) acc[j] = 0.f;

    #pragma unroll 1
    for (int half = 0; half < 2; half++) {
        __syncthreads();
        // coalesced staging: 1024 float4 (64 rows x 16 f4), 16 per thread
        #pragma unroll
        for (int it = 0; it < 16; it++) {
            int f = it * 64 + lane;
            int r = f >> 4;
            int c = f & 15;
            float4 v = make_float4(0.f, 0.f, 0.f, 0.f);
            if (row0 + r < N)
                v = ((const float4*)x)[(size_t)(row0 + r) * 32 + half * 16 + c];
            ((float4*)&xs[r * 68])[c] = v;
        }
        __syncthreads();
        #pragma unroll 1
        for (int k4 = 0; k4 < 16; k4++) {
            float4 xv = ((const float4*)&xs[lane * 68])[k4];
            const float* wr = &W1[(half * 64 + k4 * 4) * HID];   // wave-uniform
            #pragma unroll
            for (int kk = 0; kk < 4; kk++) {
                float xk = (&xv.x)[kk];
                #pragma unroll
                for (int j = 0; j < HID; j++)
                    acc[j] = fmaf(xk, wr[kk * HID + j], acc[j]);
            }
        }
    }

    if (row < N) {
        float dn = dis[row];
        float4* d4 = (float4*)&h1s[(size_t)row * HID];
        #pragma unroll
        for (int j4 = 0; j4 < 16; j4++)
            d4[j4] = make_float4(acc[j4 * 4] * dn, acc[j4 * 4 + 1] * dn,
                                 acc[j4 * 4 + 2] * dn, acc[j4 * 4 + 3] * dn);
    }
}

// ---------- fused layer-1 agg + ReLU + W2 GEMM: one wave per node ----------
__global__ __launch_bounds__(256) void agg1_fused(
        const int* __restrict__ row_ptr, const int* __restrict__ csr_src,
        const float* __restrict__ h1s, const float* __restrict__ dis,
        const float* __restrict__ b1, const float* __restrict__ W2,
        float* __restrict__ h2s, int N) {
    __shared__ float W2s[HID * NCLS];
    __shared__ float ts[4][HID];
    int tid = threadIdx.x;
    for (int i = tid; i < HID * NCLS; i += 256) W2s[i] = W2[i];
    __syncthreads();

    int w = tid >> 6;
    int lane = tid & 63;
    int n = blockIdx.x * 4 + w;

    float acc = 0.f;
    float dn = 0.f;
    if (n < N) {
        dn = dis[n];
        int beg = row_ptr[n];
        int end = row_ptr[n + 1];
        int i = beg;
        for (; i + 4 <= end; i += 4) {
            int s0 = csr_src[i];
            int s1 = csr_src[i + 1];
            int s2 = csr_src[i + 2];
            int s3 = csr_src[i + 3];
            float v0 = h1s[(size_t)s0 * HID + lane];
            float v1 = h1s[(size_t)s1 * HID + lane];
            float v2 = h1s[(size_t)s2 * HID + lane];
            float v3 = h1s[(size_t)s3 * HID + lane];
            acc += v0 + v1 + v2 + v3;
        }
        for (; i < end; i++)
            acc += h1s[(size_t)csr_src[i] * HID + lane];
    }

    float t = fmaxf(dn * acc + b1[lane], 0.f);
    ts[w][lane] = t;

    int q = lane >> 4;
    int c = lane & 15;
    float p = 0.f;
    #pragma unroll
    for (int jj = 0; jj < 16; jj++) {
        int j = q * 16 + jj;
        p += ts[w][j] * W2s[j * NCLS + c];
    }
    p += __shfl_xor(p, 16, 64);
    p += __shfl_xor(p, 32, 64);
    if (n < N && q == 0) h2s[(size_t)n * NCLS + c] = p * dn;
}

// ---------- fused layer-2 agg + epilogue ----------
__global__ __launch_bounds__(256) void agg2_fused(
        const int* __restrict__ row_ptr, const int* __restrict__ csr_src,
        const float* __restrict__ h2s, const float* __restrict__ dis,
        const float* __restrict__ b2, float* __restrict__ out, int N) {
    int tid = blockIdx.x * blockDim.x + threadIdx.x;
    int n = tid >> 6;
    int lane = tid & 63;
    if (n >= N) return;
    int j = lane >> 4;
    int c = lane & 15;
    int beg = row_ptr[n];
    int end = row_ptr[n + 1];
    float acc = 0.f;
    for (int i = beg + j; i < end; i += 4) {
        int s = csr_src[i];
        acc += h2s[(size_t)s * NCLS + c];
    }
    acc += __shfl_xor(acc, 16, 64);
    acc += __shfl_xor(acc, 32, 64);
    if (j == 0) out[(size_t)n * NCLS + c] = dis[n] * acc + b2[c];
}

extern "C" void kernel_launch(void* const* d_in, const int* in_sizes, int n_in,
                              void* d_out, int out_size, void* d_ws, size_t ws_size,
                              hipStream_t stream) {
    const float* x   = (const float*)d_in[0];
    const int*   src = (const int*)  d_in[1];
    const int*   dst = (const int*)  d_in[2];
    const float* W1  = (const float*)d_in[3];
    const float* b1  = (const float*)d_in[4];
    const float* W2  = (const float*)d_in[5];
    const float* b2  = (const float*)d_in[6];
    float* out = (float*)d_out;
    int E = in_sizes[1];
    int N = in_sizes[0] / F_IN;
    int NB = (N + BNODES - 1) >> BSHIFT;
    int nchunks = (E + CHUNK - 1) / CHUNK;

    char* ws = (char*)d_ws;
    size_t off = 0;
    auto alloc = [&](size_t bytes) { size_t o = off; off = (off + bytes + 255) & ~(size_t)255; return (void*)(ws + o); };
    int*   bucket_count  = (int*)  alloc((size_t)NB * 4);
    int*   bucket_base   = (int*)  alloc((size_t)(NB + 1) * 4);
    int*   bucket_cursor = (int*)  alloc((size_t)NB * 4);
    int*   row_ptr       = (int*)  alloc((size_t)(N + 1) * 4);
    int*   csr_src       = (int*)  alloc((size_t)E * 4);
    float* dis           = (float*)alloc((size_t)N * 4);
    float* h1s           = (float*)alloc((size_t)N * HID * 4);
    float* h2s           = (float*)alloc((size_t)N * NCLS * 4);
    unsigned int* part   = (unsigned int*)h1s;   // aliases h1s (dead before gemm1)

    hipMemsetAsync(bucket_count, 0, (size_t)NB * 4, stream);

    hist_kernel   <<<nchunks, 256, 0, stream>>>(dst, bucket_count, E, NB);
    scan_buckets  <<<1, 512, 0, stream>>>(bucket_count, bucket_base, bucket_cursor, row_ptr, NB, N, E);
    scatter_kernel<<<nchunks, 256, 0, stream>>>(src, dst, bucket_cursor, part, E, NB);
    csr_build     <<<NB, 256, 0, stream>>>(part, bucket_base, csr_src, row_ptr, dis, N);
    gemm1_kernel  <<<(N + 63) / 64, 64, 0, stream>>>(x, W1, dis, h1s, N);
    agg1_fused    <<<(N + 3) / 4, 256, 0, stream>>>(row_ptr, csr_src, h1s, dis, b1, W2, h2s, N);
    agg2_fused    <<<(N + 3) / 4, 256, 0, stream>>>(row_ptr, csr_src, h2s, dis, b2, out, N);
}